// Round 5
// baseline (180.608 us; speedup 1.0000x reference)
//
#include <hip/hip_runtime.h>
#include <math.h>

#define N_NODES 50000
#define N_EDGES 600000
#define DIM 128
#define BCAP 64     // CSR-path bucket capacity (legacy)
#define C8 32       // per-(dst,XCD) slot capacity: 32*4B = 128B aligned region
                    // P(Poisson(12/8) >= 32) ~ 1e-30; no cross-XCD line sharing
#define SEG (8 * C8)        // 256 ints per dst in lst
#define PADN 50048          // cur8 slice stride (128B-aligned slice separation)

typedef __attribute__((ext_vector_type(8))) short bf16x8;
typedef __attribute__((ext_vector_type(4))) float f32x4;

// HW packed f32->bf16 RNE (identical bits to the bit-twiddle path).
static __device__ __forceinline__ unsigned cvt_pk_bf16(float a, float b) {
    unsigned r;
    asm("v_cvt_pk_bf16_f32 %0, %1, %2" : "=v"(r) : "v"(a), "v"(b));
    return r;
}
static __device__ __forceinline__ unsigned short f2bf(float f) {
    return (unsigned short)cvt_pk_bf16(f, f);
}

// physical XCD id (0..7), wave-uniform. [measured: learn_hip m09]
static __device__ __forceinline__ unsigned xcc_id() {
    unsigned x;
    asm volatile("s_getreg_b32 %0, hwreg(HW_REG_XCC_ID)" : "=s"(x));
    return x & 7u;
}

// unpack one u32 (two bf16) -> two floats
#define UNPK(w, d0, d1)                         \
    d0 = __uint_as_float((w) << 16);            \
    d1 = __uint_as_float((w) & 0xFFFF0000u);

// sum across each 16-lane row via DPP (VALU pipe; no LDS latency).
#define DPPADD(x, ctrl)                                                          \
    x += __int_as_float(__builtin_amdgcn_mov_dpp(__float_as_int(x), ctrl,        \
                                                 0xF, 0xF, true));
static __device__ __forceinline__ float row_sum16(float x) {
    DPPADD(x, 0xB1)    // quad_perm [1,0,3,2]  (xor 1)
    DPPADD(x, 0x4E)    // quad_perm [2,3,0,1]  (xor 2)
    DPPADD(x, 0x141)   // row_half_mirror
    DPPADD(x, 0x140)   // row_mirror
    return x;
}

// ---------------- prep: zero per-XCD cursors + cnt + convert W to bf16
__global__ __launch_bounds__(256) void prep_kernel(const float* __restrict__ W,
                                                   unsigned short* __restrict__ Wb,
                                                   int* __restrict__ cur8,
                                                   int* __restrict__ cnt) {
    int gid = blockIdx.x * 256 + threadIdx.x;
    if (gid < N_NODES) {
        #pragma unroll
        for (int x = 0; x < 8; ++x) cur8[x * PADN + gid] = 0;
        cnt[gid] = 0;
    }
    if (gid < DIM * DIM) Wb[gid] = f2bf(W[gid]);
}

// ---------------- gemm body: z = h @ W^T via bf16 MFMA, fp32 acc, bf16 out
static __device__ __forceinline__ void gemm_body(const float* __restrict__ h,
                                                 const unsigned short* __restrict__ Wb,
                                                 unsigned short* __restrict__ zb,
                                                 int wave, int lane) {
    int lo = lane & 15;
    int hi = lane >> 4;
    long row0 = (long)wave * 16;

    bf16x8 afrag[4];
    const float* arow = h + (row0 + lo) * DIM;
    #pragma unroll
    for (int kt = 0; kt < 4; ++kt) {
        const float* ap = arow + kt * 32 + hi * 8;
        float4 f0 = *(const float4*)ap;
        float4 f1 = *(const float4*)(ap + 4);
        union { unsigned u[4]; bf16x8 v; } c;
        c.u[0] = cvt_pk_bf16(f0.x, f0.y);
        c.u[1] = cvt_pk_bf16(f0.z, f0.w);
        c.u[2] = cvt_pk_bf16(f1.x, f1.y);
        c.u[3] = cvt_pk_bf16(f1.z, f1.w);
        afrag[kt] = c.v;
    }

    #pragma unroll
    for (int ct = 0; ct < 8; ++ct) {
        f32x4 acc = {0.f, 0.f, 0.f, 0.f};
        const unsigned short* brow = Wb + (ct * 16 + lo) * DIM + hi * 8;
        #pragma unroll
        for (int kt = 0; kt < 4; ++kt) {
            bf16x8 b = *(const bf16x8*)(brow + kt * 32);
            acc = __builtin_amdgcn_mfma_f32_16x16x32_bf16(afrag[kt], b, acc, 0, 0, 0);
        }
        // D: row = hi*4 + r, col = lo  (m89-verified C/D layout)
        unsigned short* zp = zb + (row0 + hi * 4) * DIM + ct * 16 + lo;
        zp[0 * DIM] = f2bf(acc[0]);
        zp[1 * DIM] = f2bf(acc[1]);
        zp[2 * DIM] = f2bf(acc[2]);
        zp[3 * DIM] = f2bf(acc[3]);
    }
}

// Concurrent fill || gemm via block-role partition (bid%4==0 -> gemm).
// Fill now uses XCD-LOCAL L2 atomics: per-XCD cursor slice (cur8[xcd*PADN+d])
// + per-XCD 128B slot segment (lst[d*SEG + xcd*C8 + pos]). No memory-side
// atomic RMW traffic (round-4 showed ~31MB of line-granular RMW writes =
// the fg bottleneck). Visibility to node_kernel via dispatch-boundary flush.
__global__ __launch_bounds__(256) void fg_kernel(const float* __restrict__ h,
                                                 const unsigned short* __restrict__ Wb,
                                                 unsigned short* __restrict__ zb,
                                                 const int* __restrict__ src,
                                                 const int* __restrict__ dst,
                                                 int* __restrict__ cur8,
                                                 int* __restrict__ lst) {
    int bid = blockIdx.x;
    if (bid & 3) {
        int f = (bid >> 2) * 3 + (bid & 3) - 1;   // fill-block index 0..2343
        int i = f * 256 + threadIdx.x;
        if (i < N_EDGES) {
            int d = dst[i];
            unsigned x = xcc_id();
            int pos = __hip_atomic_fetch_add(cur8 + x * PADN + d, 1,
                                             __ATOMIC_RELAXED,
                                             __HIP_MEMORY_SCOPE_WORKGROUP);
            if (pos < C8) lst[d * SEG + x * C8 + pos] = src[i];
        }
        return;
    }
    int wave = (bid >> 2) * 4 + (threadIdx.x >> 6);
    if (wave >= N_NODES / 16) return;
    gemm_body(h, Wb, zb, wave, threadIdx.x & 63);
}

// standalone gemm for the CSR fallback path
__global__ __launch_bounds__(256) void gemm_kernel(const float* __restrict__ h,
                                                   const unsigned short* __restrict__ Wb,
                                                   unsigned short* __restrict__ zb) {
    int wave = blockIdx.x * 4 + (threadIdx.x >> 6);
    if (wave >= N_NODES / 16) return;
    gemm_body(h, Wb, zb, wave, threadIdx.x & 63);
}

// ---------------- CSR fallback path: count / scan / fill
__global__ __launch_bounds__(256) void count_kernel(const int* __restrict__ dst,
                                                    int* __restrict__ cnt) {
    int i = blockIdx.x * 256 + threadIdx.x;
    if (i < N_EDGES) atomicAdd(cnt + dst[i], 1);
}

__global__ __launch_bounds__(256) void scan_a(const int* __restrict__ cnt,
                                              int* __restrict__ incl,
                                              int* __restrict__ bsum) {
    __shared__ int s[256];
    int i = blockIdx.x * 256 + threadIdx.x;
    s[threadIdx.x] = (i < N_NODES) ? cnt[i] : 0;
    __syncthreads();
    #pragma unroll
    for (int off = 1; off < 256; off <<= 1) {
        int t = (threadIdx.x >= off) ? s[threadIdx.x - off] : 0;
        __syncthreads();
        s[threadIdx.x] += t;
        __syncthreads();
    }
    if (i < N_NODES) incl[i] = s[threadIdx.x];
    if (threadIdx.x == 255) bsum[blockIdx.x] = s[255];
}

__global__ __launch_bounds__(256) void scan_b(int* __restrict__ bsum, int nb) {
    __shared__ int s[256];
    s[threadIdx.x] = (threadIdx.x < nb) ? bsum[threadIdx.x] : 0;
    __syncthreads();
    #pragma unroll
    for (int off = 1; off < 256; off <<= 1) {
        int t = (threadIdx.x >= off) ? s[threadIdx.x - off] : 0;
        __syncthreads();
        s[threadIdx.x] += t;
        __syncthreads();
    }
    if (threadIdx.x < nb) bsum[threadIdx.x] = s[threadIdx.x];
}

__global__ __launch_bounds__(256) void scan_c(int* __restrict__ incl_off,
                                              const int* __restrict__ cnt,
                                              const int* __restrict__ bsum) {
    int i = blockIdx.x * 256 + threadIdx.x;
    if (i >= N_NODES) return;
    int base = (blockIdx.x > 0) ? bsum[blockIdx.x - 1] : 0;
    incl_off[i] = incl_off[i] - cnt[i] + base;
}

__global__ __launch_bounds__(256) void cfill_kernel(const int* __restrict__ src,
                                                    const int* __restrict__ dst,
                                                    const int* __restrict__ off,
                                                    int* __restrict__ cur,
                                                    int* __restrict__ lst) {
    int i = blockIdx.x * 256 + threadIdx.x;
    if (i >= N_EDGES) return;
    int d = dst[i];
    int pos = atomicAdd(cur + d, 1);
    lst[off[d] + pos] = src[i];
}

// ---------------- fused per-node (bucket path): one node per WAVE (best
// measured structure: all 4 quarters read the SAME rows -> 64-lane access
// dedups to one 256B fetch). Edge list is 8 per-XCD segments; lane j maps to
// (xcd,pos) via branchless prefix walk over the 8 counts. Inner loop unrolled
// 4-wide: 4 independent gathers in flight per wave (untested axis on this
// structure; rounds 2-3 regressions were confounded with fewer-fatter waves).
__global__ __launch_bounds__(256) void node_kernel(const unsigned short* __restrict__ zb,
                                                   const int* __restrict__ lst,
                                                   const int* __restrict__ cur8,
                                                   const float* __restrict__ beta,
                                                   float* __restrict__ out) {
    int node = blockIdx.x * 4 + (threadIdx.x >> 6);
    if (node >= N_NODES) return;
    int lane = threadIdx.x & 63;
    int q = lane >> 4;
    int ql = lane & 15;

    // per-XCD counts -> deg + lane->slot map (broadcast loads, L1/L2-hit)
    int c[8];
    int deg = 0;
    #pragma unroll
    for (int x = 0; x < 8; ++x) {
        int v = cur8[x * PADN + node];
        v = (v > C8) ? C8 : v;    // overflow guard (never hit for Poisson(12))
        c[x] = v;
        deg += v;
    }
    float nbet = -beta[0];

    // zd dims ql*8..+7 (all 4 quarters read the same 256B row -> broadcast)
    uint4 zdw = *(const uint4*)(zb + (long)node * DIM + ql * 8);
    float zd[8];
    UNPK(zdw.x, zd[0], zd[1]) UNPK(zdw.y, zd[2], zd[3])
    UNPK(zdw.z, zd[4], zd[5]) UNPK(zdw.w, zd[6], zd[7])

    float sden = 0.0f;     // per-quarter partial denom
    float acc[8];
    #pragma unroll
    for (int i = 0; i < 8; ++i) acc[i] = 0.0f;

    for (int cb = 0; cb < deg; cb += 64) {
        int nch = deg - cb;
        if (nch > 64) nch = 64;
        // lane j holds src of edge cb+j: map j -> segment x, slot j-P[x]
        int j = cb + lane;
        int offw = 0, p = 0;
        #pragma unroll
        for (int x = 0; x < 8; ++x) {
            if (j >= p && j < p + c[x]) offw = x * C8 + (j - p);
            p += c[x];
        }
        int sj = (lane < nch) ? lst[(long)node * SEG + offw] : 0;

        for (int jb = 0; jb < nch; jb += 16) {
            int sv[4];
            bool vv[4];
            #pragma unroll
            for (int k = 0; k < 4; ++k) {
                int jo = jb + k * 4 + q;         // quarter q's 4 edge slots
                vv[k] = jo < nch;
                sv[k] = __shfl(sj, vv[k] ? jo : 0, 64);
            }
            uint4 aw[4];
            #pragma unroll
            for (int k = 0; k < 4; ++k)          // 4 gathers in flight
                aw[k] = *(const uint4*)(zb + (long)sv[k] * DIM + ql * 8);

            #pragma unroll
            for (int k = 0; k < 4; ++k) {
                float a[8];
                UNPK(aw[k].x, a[0], a[1]) UNPK(aw[k].y, a[2], a[3])
                UNPK(aw[k].z, a[4], a[5]) UNPK(aw[k].w, a[6], a[7])
                float pk = 0.0f;
                #pragma unroll
                for (int i = 0; i < 8; ++i) {
                    float d = a[i] - zd[i];
                    pk += d * d;
                }
                pk = row_sum16(pk);              // full ||z_s - z_d||^2
                float w = vv[k]
                        ? __expf(nbet * __builtin_amdgcn_sqrtf(pk + 1e-12f))
                        : 0.0f;
                sden += w;
                #pragma unroll
                for (int i = 0; i < 8; ++i) acc[i] += w * a[i];
            }
        }
    }

    // combine the 4 quarters
    #define CMB(v) v += __shfl_xor(v, 16, 64); v += __shfl_xor(v, 32, 64);
    CMB(sden)
    CMB(acc[0]) CMB(acc[1]) CMB(acc[2]) CMB(acc[3])
    CMB(acc[4]) CMB(acc[5]) CMB(acc[6]) CMB(acc[7])
    #undef CMB

    float inv = (deg > 0) ? 1.0f / sden : 0.0f;
    if (q == 0) {
        float* orow = out + (long)node * DIM + ql * 8;
        *(float4*)orow =
            make_float4(acc[0] * inv, acc[1] * inv, acc[2] * inv, acc[3] * inv);
        *(float4*)(orow + 4) =
            make_float4(acc[4] * inv, acc[5] * inv, acc[6] * inv, acc[7] * inv);
    }
}

// CSR-path node kernel (round-0 form, unchanged; fallback only)
__global__ __launch_bounds__(256) void node_csr(const unsigned short* __restrict__ zb,
                                                const int* __restrict__ lst,
                                                const int* __restrict__ off,
                                                const int* __restrict__ degp,
                                                const float* __restrict__ beta,
                                                float* __restrict__ out) {
    int node = blockIdx.x * 4 + (threadIdx.x >> 6);
    if (node >= N_NODES) return;
    int lane = threadIdx.x & 63;
    int q = lane >> 4;
    int ql = lane & 15;
    int deg = degp[node];
    int start = off[node];
    float nbet = -beta[0];

    uint4 zdw = *(const uint4*)(zb + (long)node * DIM + ql * 8);
    float zd[8];
    UNPK(zdw.x, zd[0], zd[1]) UNPK(zdw.y, zd[2], zd[3])
    UNPK(zdw.z, zd[4], zd[5]) UNPK(zdw.w, zd[6], zd[7])

    float sden = 0.0f;
    float acc[8];
    #pragma unroll
    for (int i = 0; i < 8; ++i) acc[i] = 0.0f;

    for (int cb = 0; cb < deg; cb += 64) {
        int nch = deg - cb;
        if (nch > 64) nch = 64;
        int sj = (lane < nch) ? lst[start + cb + lane] : 0;

        for (int jb = 0; jb < nch; jb += 8) {
            int jo0 = jb + q;
            int jo1 = jb + 4 + q;
            bool v0 = jo0 < nch;
            bool v1 = jo1 < nch;
            int s0 = __shfl(sj, v0 ? jo0 : 0, 64);
            int s1 = __shfl(sj, v1 ? jo1 : 0, 64);
            uint4 aw0 = *(const uint4*)(zb + (long)s0 * DIM + ql * 8);
            uint4 aw1 = *(const uint4*)(zb + (long)s1 * DIM + ql * 8);
            float a0[8], a1[8];
            UNPK(aw0.x, a0[0], a0[1]) UNPK(aw0.y, a0[2], a0[3])
            UNPK(aw0.z, a0[4], a0[5]) UNPK(aw0.w, a0[6], a0[7])
            UNPK(aw1.x, a1[0], a1[1]) UNPK(aw1.y, a1[2], a1[3])
            UNPK(aw1.z, a1[4], a1[5]) UNPK(aw1.w, a1[6], a1[7])

            float p0 = 0.0f, p1 = 0.0f;
            #pragma unroll
            for (int i = 0; i < 8; ++i) {
                float d0 = a0[i] - zd[i];
                p0 += d0 * d0;
                float d1 = a1[i] - zd[i];
                p1 += d1 * d1;
            }
            p0 = row_sum16(p0);
            p1 = row_sum16(p1);
            float w0 = v0 ? __expf(nbet * __builtin_amdgcn_sqrtf(p0 + 1e-12f)) : 0.0f;
            float w1 = v1 ? __expf(nbet * __builtin_amdgcn_sqrtf(p1 + 1e-12f)) : 0.0f;
            sden += w0 + w1;
            #pragma unroll
            for (int i = 0; i < 8; ++i) acc[i] += w0 * a0[i] + w1 * a1[i];
        }
    }

    #define CMB(v) v += __shfl_xor(v, 16, 64); v += __shfl_xor(v, 32, 64);
    CMB(sden)
    CMB(acc[0]) CMB(acc[1]) CMB(acc[2]) CMB(acc[3])
    CMB(acc[4]) CMB(acc[5]) CMB(acc[6]) CMB(acc[7])
    #undef CMB

    float inv = (deg > 0) ? 1.0f / sden : 0.0f;
    if (q == 0) {
        float* orow = out + (long)node * DIM + ql * 8;
        *(float4*)orow =
            make_float4(acc[0] * inv, acc[1] * inv, acc[2] * inv, acc[3] * inv);
        *(float4*)(orow + 4) =
            make_float4(acc[4] * inv, acc[5] * inv, acc[6] * inv, acc[7] * inv);
    }
}

extern "C" void kernel_launch(void* const* d_in, const int* in_sizes, int n_in,
                              void* d_out, int out_size, void* d_ws, size_t ws_size,
                              hipStream_t stream) {
    const float* h    = (const float*)d_in[0];
    const float* W    = (const float*)d_in[1];
    const float* beta = (const float*)d_in[2];
    const int* src    = (const int*)d_in[3];
    const int* dst    = (const int*)d_in[4];
    float* out = (float*)d_out;

    // workspace (4B word units).
    //   zb    [0, 3.2M)                      50000*128 bf16
    //   lst   [3.2M, 3.2M+12.8M)             bucket: 50000*SEG ints (51.2MB)
    //                                        csr:    600k ints (overlaid)
    //   cur8  8*PADN = 400,384 words         per-XCD cursors (line-padded)
    //   cnt / off / bsum / Wb after
    const size_t lst_words_bucket = (size_t)N_NODES * SEG;          // 12.8M
    const size_t bucket_total =
        (3200000ull + lst_words_bucket + 8ull * PADN + 100000 + 256 + 8192) * 4;
    const bool use_bucket = ws_size >= bucket_total;
    const size_t lst_len = use_bucket ? lst_words_bucket : 600000;

    float* ws  = (float*)d_ws;
    unsigned short* zb = (unsigned short*)ws;            // 3,200,000 words
    int* lst   = (int*)(ws + 3200000);                   // see above
    int* cur8  = (int*)(ws + 3200000 + lst_len);         // 8*PADN
    int* cnt   = cur8 + 8 * PADN;                        // 50,000
    int* off   = cnt + 50000;                            // 50,000
    int* bsum  = off + 50000;                            //    256
    unsigned short* Wb = (unsigned short*)(bsum + 256);  // 16,384 bf16

    prep_kernel<<<196, 256, 0, stream>>>(W, Wb, cur8, cnt);
    if (use_bucket) {
        // 3126 blocks: bid%4==0 -> gemm (782), else -> fill (2344)
        fg_kernel<<<3126, 256, 0, stream>>>(h, Wb, zb, src, dst, cur8, lst);
        node_kernel<<<N_NODES / 4, 256, 0, stream>>>(zb, lst, cur8, beta, out);
    } else {
        count_kernel<<<(N_EDGES + 255) / 256, 256, 0, stream>>>(dst, cnt);
        scan_a<<<196, 256, 0, stream>>>(cnt, off, bsum);
        scan_b<<<1, 256, 0, stream>>>(bsum, 196);
        scan_c<<<196, 256, 0, stream>>>(off, cnt, bsum);
        // reuse cur8 slice 0 as the csr cursor (zeroed by prep)
        cfill_kernel<<<(N_EDGES + 255) / 256, 256, 0, stream>>>(src, dst, off, cur8, lst);
        gemm_kernel<<<(N_NODES / 16 + 3) / 4, 256, 0, stream>>>(h, Wb, zb);
        node_csr<<<N_NODES / 4, 256, 0, stream>>>(zb, lst, off, cnt, beta, out);
    }
}

// Round 6
// 137.860 us; speedup vs baseline: 1.3101x; 1.3101x over previous
//
#include <hip/hip_runtime.h>
#include <math.h>

#define N_NODES 50000
#define N_EDGES 600000
#define DIM 128
#define BCAP 60     // slots per dst; max observed deg for Binomial(600k,1/50k) ~ 30
#define NRANGE 196  // dst ranges of 256 dsts (50000 -> 196 ranges)
#define RCAP 4096   // elog capacity per range (mean 3072, sigma 55; +8sigma < 3600)
#define EPB 2048    // edges per pass-1 block
#define NB1 293     // ceil(600000/2048)

typedef __attribute__((ext_vector_type(8))) short bf16x8;
typedef __attribute__((ext_vector_type(4))) float f32x4;

// HW packed f32->bf16 RNE (identical bits to the bit-twiddle path).
static __device__ __forceinline__ unsigned cvt_pk_bf16(float a, float b) {
    unsigned r;
    asm("v_cvt_pk_bf16_f32 %0, %1, %2" : "=v"(r) : "v"(a), "v"(b));
    return r;
}
static __device__ __forceinline__ unsigned short f2bf(float f) {
    return (unsigned short)cvt_pk_bf16(f, f);
}

// unpack one u32 (two bf16) -> two floats
#define UNPK(w, d0, d1)                         \
    d0 = __uint_as_float((w) << 16);            \
    d1 = __uint_as_float((w) & 0xFFFF0000u);

// sum across each 16-lane row via DPP (VALU pipe; no LDS latency).
#define DPPADD(x, ctrl)                                                          \
    x += __int_as_float(__builtin_amdgcn_mov_dpp(__float_as_int(x), ctrl,        \
                                                 0xF, 0xF, true));
static __device__ __forceinline__ float row_sum16(float x) {
    DPPADD(x, 0xB1)    // quad_perm [1,0,3,2]  (xor 1)
    DPPADD(x, 0x4E)    // quad_perm [2,3,0,1]  (xor 2)
    DPPADD(x, 0x141)   // row_half_mirror
    DPPADD(x, 0x140)   // row_mirror
    return x;
}

// ---------------- prep: zero cursors + convert W to bf16
__global__ __launch_bounds__(256) void prep_kernel(const float* __restrict__ W,
                                                   unsigned short* __restrict__ Wb,
                                                   int* __restrict__ rngcur,
                                                   int* __restrict__ cur,
                                                   int* __restrict__ cnt) {
    int gid = blockIdx.x * 256 + threadIdx.x;
    if (gid < 256) rngcur[gid] = 0;
    if (gid < N_NODES) {
        cur[gid] = 0;
        cnt[gid] = 0;
    }
    if (gid < DIM * DIM) Wb[gid] = f2bf(W[gid]);
}

// ---------------- gemm body: z = h @ W^T via bf16 MFMA, fp32 acc, bf16 out
static __device__ __forceinline__ void gemm_body(const float* __restrict__ h,
                                                 const unsigned short* __restrict__ Wb,
                                                 unsigned short* __restrict__ zb,
                                                 int wave, int lane) {
    int lo = lane & 15;
    int hi = lane >> 4;
    long row0 = (long)wave * 16;

    bf16x8 afrag[4];
    const float* arow = h + (row0 + lo) * DIM;
    #pragma unroll
    for (int kt = 0; kt < 4; ++kt) {
        const float* ap = arow + kt * 32 + hi * 8;
        float4 f0 = *(const float4*)ap;
        float4 f1 = *(const float4*)(ap + 4);
        union { unsigned u[4]; bf16x8 v; } c;
        c.u[0] = cvt_pk_bf16(f0.x, f0.y);
        c.u[1] = cvt_pk_bf16(f0.z, f0.w);
        c.u[2] = cvt_pk_bf16(f1.x, f1.y);
        c.u[3] = cvt_pk_bf16(f1.z, f1.w);
        afrag[kt] = c.v;
    }

    #pragma unroll
    for (int ct = 0; ct < 8; ++ct) {
        f32x4 acc = {0.f, 0.f, 0.f, 0.f};
        const unsigned short* brow = Wb + (ct * 16 + lo) * DIM + hi * 8;
        #pragma unroll
        for (int kt = 0; kt < 4; ++kt) {
            bf16x8 b = *(const bf16x8*)(brow + kt * 32);
            acc = __builtin_amdgcn_mfma_f32_16x16x32_bf16(afrag[kt], b, acc, 0, 0, 0);
        }
        // D: row = hi*4 + r, col = lo  (m89-verified C/D layout)
        unsigned short* zp = zb + (row0 + hi * 4) * DIM + ct * 16 + lo;
        zp[0 * DIM] = f2bf(acc[0]);
        zp[1 * DIM] = f2bf(acc[1]);
        zp[2 * DIM] = f2bf(acc[2]);
        zp[3 * DIM] = f2bf(acc[3]);
    }
}

// ---------------- fused: pass-1 coarse radix partition (blocks 0..NB1-1) ||
// gemm (blocks NB1..NB1+781). Pass-1 replaces 600k random device-atomic RMWs
// (the measured ~70us fill floor, invariant across R1-R5 rearrangements) with
// LDS histograms + 57k grouped global atomics + run-coalesced 8B writes.
__global__ __launch_bounds__(256) void fgp1_kernel(const float* __restrict__ h,
                                                   const unsigned short* __restrict__ Wb,
                                                   unsigned short* __restrict__ zb,
                                                   const int* __restrict__ src,
                                                   const int* __restrict__ dst,
                                                   int* __restrict__ rngcur,
                                                   int2* __restrict__ elog) {
    int bid = blockIdx.x;
    if (bid < NB1) {
        __shared__ int hist[256];
        __shared__ int hbase[256];
        int tid = threadIdx.x;
        hist[tid] = 0;
        __syncthreads();

        int myd[8], mys[8];
        #pragma unroll
        for (int k = 0; k < 8; ++k) {
            int i = bid * EPB + k * 256 + tid;
            if (i < N_EDGES) {
                myd[k] = dst[i];
                mys[k] = src[i];
            } else {
                myd[k] = -1;
            }
        }
        #pragma unroll
        for (int k = 0; k < 8; ++k)
            if (myd[k] >= 0) atomicAdd(&hist[myd[k] >> 8], 1);
        __syncthreads();

        if (tid < NRANGE) {
            int hv = hist[tid];
            hbase[tid] = hv ? atomicAdd(rngcur + tid, hv) : 0;
        }
        __syncthreads();
        hist[tid] = 0;          // reuse as local cursor
        __syncthreads();

        #pragma unroll
        for (int k = 0; k < 8; ++k) {
            if (myd[k] >= 0) {
                int r = myd[k] >> 8;
                int p = atomicAdd(&hist[r], 1);
                int gp = r * RCAP + hbase[r] + p;   // hbase+p < RCAP (8-sigma margin)
                elog[gp] = make_int2(mys[k], myd[k]);
            }
        }
        return;
    }
    int wave = (bid - NB1) * 4 + (threadIdx.x >> 6);
    if (wave >= N_NODES / 16) return;
    gemm_body(h, Wb, zb, wave, threadIdx.x & 63);
}

// ---------------- pass 2: one block per dst-range. Build the whole 256-dst
// bucket array in LDS (LDS atomics ~free), stream out dense lst + counts with
// full-line coalesced writes (no RFO, no per-edge device atomics).
__global__ __launch_bounds__(1024) void p2_kernel(const int2* __restrict__ elog,
                                                  const int* __restrict__ rngcur,
                                                  int* __restrict__ lst,
                                                  int* __restrict__ cnt) {
    __shared__ int lcnt[256];
    __shared__ int slot[256 * BCAP];    // 61440B; +1KB cnt = 62.4KB LDS
    int r = blockIdx.x;
    int tid = threadIdx.x;
    if (tid < 256) lcnt[tid] = 0;
    __syncthreads();

    int n = rngcur[r];
    if (n > RCAP) n = RCAP;
    for (int i = tid; i < n; i += 1024) {
        int2 e = elog[(long)r * RCAP + i];
        int ld = e.y & 255;
        int p = atomicAdd(&lcnt[ld], 1);
        if (p < BCAP) slot[ld * BCAP + p] = e.x;
    }
    __syncthreads();

    int d0 = r * 256;
    if (tid < 256 && d0 + tid < N_NODES) {
        int c = lcnt[tid];
        cnt[d0 + tid] = (c > BCAP) ? BCAP : c;   // clamp (unreachable: max deg ~30)
    }
    // dense streaming write; slots beyond count are garbage but never read
    for (int k = tid; k < 256 * BCAP; k += 1024)
        lst[(long)r * 256 * BCAP + k] = slot[k];
}

// standalone gemm for the CSR fallback path
__global__ __launch_bounds__(256) void gemm_kernel(const float* __restrict__ h,
                                                   const unsigned short* __restrict__ Wb,
                                                   unsigned short* __restrict__ zb) {
    int wave = blockIdx.x * 4 + (threadIdx.x >> 6);
    if (wave >= N_NODES / 16) return;
    gemm_body(h, Wb, zb, wave, threadIdx.x & 63);
}

// ---------------- CSR fallback path: count / scan / fill
__global__ __launch_bounds__(256) void count_kernel(const int* __restrict__ dst,
                                                    int* __restrict__ cnt) {
    int i = blockIdx.x * 256 + threadIdx.x;
    if (i < N_EDGES) atomicAdd(cnt + dst[i], 1);
}

__global__ __launch_bounds__(256) void scan_a(const int* __restrict__ cnt,
                                              int* __restrict__ incl,
                                              int* __restrict__ bsum) {
    __shared__ int s[256];
    int i = blockIdx.x * 256 + threadIdx.x;
    s[threadIdx.x] = (i < N_NODES) ? cnt[i] : 0;
    __syncthreads();
    #pragma unroll
    for (int off = 1; off < 256; off <<= 1) {
        int t = (threadIdx.x >= off) ? s[threadIdx.x - off] : 0;
        __syncthreads();
        s[threadIdx.x] += t;
        __syncthreads();
    }
    if (i < N_NODES) incl[i] = s[threadIdx.x];
    if (threadIdx.x == 255) bsum[blockIdx.x] = s[255];
}

__global__ __launch_bounds__(256) void scan_b(int* __restrict__ bsum, int nb) {
    __shared__ int s[256];
    s[threadIdx.x] = (threadIdx.x < nb) ? bsum[threadIdx.x] : 0;
    __syncthreads();
    #pragma unroll
    for (int off = 1; off < 256; off <<= 1) {
        int t = (threadIdx.x >= off) ? s[threadIdx.x - off] : 0;
        __syncthreads();
        s[threadIdx.x] += t;
        __syncthreads();
    }
    if (threadIdx.x < nb) bsum[threadIdx.x] = s[threadIdx.x];
}

__global__ __launch_bounds__(256) void scan_c(int* __restrict__ incl_off,
                                              const int* __restrict__ cnt,
                                              const int* __restrict__ bsum) {
    int i = blockIdx.x * 256 + threadIdx.x;
    if (i >= N_NODES) return;
    int base = (blockIdx.x > 0) ? bsum[blockIdx.x - 1] : 0;
    incl_off[i] = incl_off[i] - cnt[i] + base;
}

__global__ __launch_bounds__(256) void cfill_kernel(const int* __restrict__ src,
                                                    const int* __restrict__ dst,
                                                    const int* __restrict__ off,
                                                    int* __restrict__ cur,
                                                    int* __restrict__ lst) {
    int i = blockIdx.x * 256 + threadIdx.x;
    if (i >= N_EDGES) return;
    int d = dst[i];
    int pos = atomicAdd(cur + d, 1);
    lst[off[d] + pos] = src[i];
}

// ---------------- fused per-node: scores + softmax (no-max) + gather, bf16 z.
// ROUND-0 STRUCTURE (best measured): one node per WAVE, 16 lanes per edge,
// 2x unrolled => 8 edges per iteration, all 4 quarters share the same rows'
// cache lines.
__global__ __launch_bounds__(256) void node_kernel(const unsigned short* __restrict__ zb,
                                                   const int* __restrict__ lst,
                                                   const int* __restrict__ off,
                                                   const int* __restrict__ degp,
                                                   int stride,
                                                   const float* __restrict__ beta,
                                                   float* __restrict__ out) {
    int node = blockIdx.x * 4 + (threadIdx.x >> 6);
    if (node >= N_NODES) return;
    int lane = threadIdx.x & 63;
    int q = lane >> 4;
    int ql = lane & 15;
    int deg = degp[node];
    int start;
    if (stride > 0) {
        if (deg > stride) deg = stride;   // OOB guard
        start = node * stride;
    } else {
        start = off[node];
    }
    float nbet = -beta[0];

    // zd dims ql*8..+7 (all 4 quarters read the same 256B row -> broadcast)
    uint4 zdw = *(const uint4*)(zb + (long)node * DIM + ql * 8);
    float zd[8];
    UNPK(zdw.x, zd[0], zd[1]) UNPK(zdw.y, zd[2], zd[3])
    UNPK(zdw.z, zd[4], zd[5]) UNPK(zdw.w, zd[6], zd[7])

    float sden = 0.0f;     // per-quarter partial denom
    float acc[8];
    #pragma unroll
    for (int i = 0; i < 8; ++i) acc[i] = 0.0f;

    for (int cb = 0; cb < deg; cb += 64) {
        int nch = deg - cb;
        if (nch > 64) nch = 64;
        int sj = (lane < nch) ? lst[start + cb + lane] : 0;   // lane j: src of edge j

        for (int jb = 0; jb < nch; jb += 8) {
            int jo0 = jb + q;                   // this quarter's two edge slots
            int jo1 = jb + 4 + q;
            bool v0 = jo0 < nch;
            bool v1 = jo1 < nch;
            int s0 = __shfl(sj, v0 ? jo0 : 0, 64);
            int s1 = __shfl(sj, v1 ? jo1 : 0, 64);
            uint4 aw0 = *(const uint4*)(zb + (long)s0 * DIM + ql * 8);
            uint4 aw1 = *(const uint4*)(zb + (long)s1 * DIM + ql * 8);
            float a0[8], a1[8];
            UNPK(aw0.x, a0[0], a0[1]) UNPK(aw0.y, a0[2], a0[3])
            UNPK(aw0.z, a0[4], a0[5]) UNPK(aw0.w, a0[6], a0[7])
            UNPK(aw1.x, a1[0], a1[1]) UNPK(aw1.y, a1[2], a1[3])
            UNPK(aw1.z, a1[4], a1[5]) UNPK(aw1.w, a1[6], a1[7])

            float p0 = 0.0f, p1 = 0.0f;
            #pragma unroll
            for (int i = 0; i < 8; ++i) {
                float d0 = a0[i] - zd[i];
                p0 += d0 * d0;
                float d1 = a1[i] - zd[i];
                p1 += d1 * d1;
            }
            p0 = row_sum16(p0);                 // full ||z_s0 - z_d||^2 (per quarter)
            p1 = row_sum16(p1);
            float w0 = v0 ? __expf(nbet * __builtin_amdgcn_sqrtf(p0 + 1e-12f)) : 0.0f;
            float w1 = v1 ? __expf(nbet * __builtin_amdgcn_sqrtf(p1 + 1e-12f)) : 0.0f;
            sden += w0 + w1;
            #pragma unroll
            for (int i = 0; i < 8; ++i) acc[i] += w0 * a0[i] + w1 * a1[i];
        }
    }

    // combine the 4 quarters (cross-row: DPP rows are 16 lanes, so use shfl here)
    #define CMB(v) v += __shfl_xor(v, 16, 64); v += __shfl_xor(v, 32, 64);
    CMB(sden)
    CMB(acc[0]) CMB(acc[1]) CMB(acc[2]) CMB(acc[3])
    CMB(acc[4]) CMB(acc[5]) CMB(acc[6]) CMB(acc[7])
    #undef CMB

    float inv = (deg > 0) ? 1.0f / sden : 0.0f;
    if (q == 0) {
        float* orow = out + (long)node * DIM + ql * 8;
        *(float4*)orow =
            make_float4(acc[0] * inv, acc[1] * inv, acc[2] * inv, acc[3] * inv);
        *(float4*)(orow + 4) =
            make_float4(acc[4] * inv, acc[5] * inv, acc[6] * inv, acc[7] * inv);
    }
}

extern "C" void kernel_launch(void* const* d_in, const int* in_sizes, int n_in,
                              void* d_out, int out_size, void* d_ws, size_t ws_size,
                              hipStream_t stream) {
    const float* h    = (const float*)d_in[0];
    const float* W    = (const float*)d_in[1];
    const float* beta = (const float*)d_in[2];
    const int* src    = (const int*)d_in[3];
    const int* dst    = (const int*)d_in[4];
    float* out = (float*)d_out;

    // workspace (4B word units).
    //   zb     [0, 3.2M)                50000*128 bf16
    //   lst    3,010,560 words          bucket: 196*256*BCAP ints (dense d*60+p)
    //                                   csr: 600k ints (overlaid)
    //   elog   196*RCAP int2 = 1,605,632 words
    //   rngcur 256 / cnt 50k / cur 50k / off 50k / bsum 256 / Wb 8192
    const size_t lst_words_bucket = (size_t)NRANGE * 256 * BCAP;    // 3,010,560
    const size_t elog_words = (size_t)NRANGE * RCAP * 2;            // 1,605,632
    const size_t bucket_total =
        (3200000ull + lst_words_bucket + elog_words + 256 + 150000 + 256 + 8192) * 4;
    const bool use_bucket = ws_size >= bucket_total;
    const size_t lst_len = use_bucket ? lst_words_bucket : 600000;

    float* ws  = (float*)d_ws;
    unsigned short* zb = (unsigned short*)ws;            // 3,200,000 words
    int* lst    = (int*)(ws + 3200000);
    int2* elog  = (int2*)(ws + 3200000 + lst_len);       // elog_words
    int* rngcur = (int*)(ws + 3200000 + lst_len + elog_words);   // 256
    int* cnt    = rngcur + 256;                          // 50,000
    int* cur    = cnt + 50000;                           // 50,000
    int* off    = cur + 50000;                           // 50,000
    int* bsum   = off + 50000;                           //    256
    unsigned short* Wb = (unsigned short*)(bsum + 256);  // 16,384 bf16

    prep_kernel<<<196, 256, 0, stream>>>(W, Wb, rngcur, cur, cnt);
    if (use_bucket) {
        // blocks [0,293) = pass-1 partition, [293, 293+782) = gemm
        fgp1_kernel<<<NB1 + 782, 256, 0, stream>>>(h, Wb, zb, src, dst, rngcur, elog);
        p2_kernel<<<NRANGE, 1024, 0, stream>>>(elog, rngcur, lst, cnt);
        node_kernel<<<N_NODES / 4, 256, 0, stream>>>(zb, lst, off /*unused*/, cnt,
                                                     BCAP, beta, out);
    } else {
        count_kernel<<<(N_EDGES + 255) / 256, 256, 0, stream>>>(dst, cnt);
        scan_a<<<196, 256, 0, stream>>>(cnt, off, bsum);
        scan_b<<<1, 256, 0, stream>>>(bsum, 196);
        scan_c<<<196, 256, 0, stream>>>(off, cnt, bsum);
        cfill_kernel<<<(N_EDGES + 255) / 256, 256, 0, stream>>>(src, dst, off, cur, lst);
        gemm_kernel<<<(N_NODES / 16 + 3) / 4, 256, 0, stream>>>(h, Wb, zb);
        node_kernel<<<N_NODES / 4, 256, 0, stream>>>(zb, lst, off, cnt, 0, beta, out);
    }
}